// Round 5
// baseline (214.146 us; speedup 1.0000x reference)
//
#include <hip/hip_runtime.h>
#include <math.h>

#define D_MODEL 1024
#define SEQ 2048
#define SCALE 0.03125f

using bf16x8 = __attribute__((ext_vector_type(8))) short;
using f32x4  = __attribute__((ext_vector_type(4))) float;

__device__ __forceinline__ unsigned short f2bf(float f) {
  union { float f; unsigned int u; } v; v.f = f;
  return (unsigned short)((v.u + 0x7fffu + ((v.u >> 16) & 1u)) >> 16);
}

__device__ __forceinline__ void async_cp16(const void* g, void* l) {
  __builtin_amdgcn_global_load_lds(
      (const __attribute__((address_space(1))) void*)g,
      (__attribute__((address_space(3))) void*)l, 16, 0, 0);
}

// Swizzled 128x32 bf16 tile staging (R3-verified, conflict-free + coalesced):
// thread tid stages row r0=tid>>2, seg s0=(tid&3)^((r0>>1)&3) -> LDS chunk tid
// (and row r0+64 -> chunk 256+tid). Fragment b128 reads are 2-way aliased.
__device__ __forceinline__ const unsigned short* stage_ptr(
    const unsigned short* base, int row0, int ld, int tid) {
  const int r0 = tid >> 2;
  const int s0 = ((tid & 3) ^ ((r0 >> 1) & 3)) * 8;
  return base + (size_t)(row0 + r0) * ld + s0;
}

// C[128x128] = A(rows m0..) x B^T(rows n0..), K=1024, BK=32, double-buffered
// swizzled LDS, issue-ahead staging, one barrier per iter.
__device__ __forceinline__ void gemm_core(
    const unsigned short* __restrict__ gA, const unsigned short* __restrict__ gB,
    int lda, int ldb, unsigned short* As, unsigned short* Bs, int tid,
    f32x4 acc[4][4]) {
  const int lane = tid & 63, w = tid >> 6;
  const int wm = w >> 1, wn = w & 1;
  const int l16 = lane & 15, quad = lane >> 4;

  async_cp16(gA,            As + tid * 8);
  async_cp16(gA + 64 * lda, As + 2048 + tid * 8);
  async_cp16(gB,            Bs + tid * 8);
  async_cp16(gB + 64 * ldb, Bs + 2048 + tid * 8);
  __syncthreads();

  #pragma unroll 2
  for (int kk = 0; kk < 32; ++kk) {
    const int cur = (kk & 1) * 4096;
    const int nxt = 4096 - cur;
    if (kk < 31) {
      const unsigned short* a = gA + (kk + 1) * 32;
      const unsigned short* b = gB + (kk + 1) * 32;
      async_cp16(a,            As + nxt + tid * 8);
      async_cp16(a + 64 * lda, As + nxt + 2048 + tid * 8);
      async_cp16(b,            Bs + nxt + tid * 8);
      async_cp16(b + 64 * ldb, Bs + nxt + 2048 + tid * 8);
    }
    bf16x8 afr[4], bfr[4];
    #pragma unroll
    for (int mt = 0; mt < 4; mt++) {
      const int R = wm * 64 + mt * 16 + l16;
      afr[mt] = *(const bf16x8*)(As + cur + (R * 4 + (quad ^ ((R >> 1) & 3))) * 8);
    }
    #pragma unroll
    for (int nt = 0; nt < 4; nt++) {
      const int R = wn * 64 + nt * 16 + l16;
      bfr[nt] = *(const bf16x8*)(Bs + cur + (R * 4 + (quad ^ ((R >> 1) & 3))) * 8);
    }
    #pragma unroll
    for (int mt = 0; mt < 4; mt++)
      #pragma unroll
      for (int nt = 0; nt < 4; nt++)
        acc[mt][nt] = __builtin_amdgcn_mfma_f32_16x16x32_bf16(
            afr[mt], bfr[nt], acc[mt][nt], 0, 0, 0);
    __syncthreads();
  }
}

__device__ __forceinline__ void store_c_bf16(f32x4 acc[4][4],
                                             unsigned short* C, int ldc,
                                             int m0, int n0, int tid) {
  const int lane = tid & 63, w = tid >> 6;
  const int wm = w >> 1, wn = w & 1;
  const int l16 = lane & 15, quad = lane >> 4;
  #pragma unroll
  for (int mt = 0; mt < 4; mt++) {
    #pragma unroll
    for (int r = 0; r < 4; r++) {
      const int row = m0 + wm * 64 + mt * 16 + quad * 4 + r;
      unsigned short* cp = C + (size_t)row * ldc + n0 + wn * 64 + l16;
      #pragma unroll
      for (int nt = 0; nt < 4; nt++) cp[nt * 16] = f2bf(acc[mt][nt][r]);
    }
  }
}

// ---- prep: xb=bf16(x); Wqb/Wkb=bf16(W); Wsp rows {u=Wq.bk, v=Wk.bq, Wo};
//      sc = scale*(bq.bk). Pure streaming, no cross-kernel deps upstream. ----
__global__ __launch_bounds__(256) void prep_kernel(
    const float* __restrict__ x, const float* __restrict__ Wq,
    const float* __restrict__ Wk, const float* __restrict__ bq,
    const float* __restrict__ bk, const float* __restrict__ Wo,
    unsigned short* __restrict__ xb, unsigned short* __restrict__ Wqb,
    unsigned short* __restrict__ Wkb, unsigned short* __restrict__ Wsp,
    float* __restrict__ sc) {
  const int bid = blockIdx.x, tid = threadIdx.x;
  if (bid < 8192) {  // x rows -> bf16
    const float4 xv = ((const float4*)(x + (size_t)bid * D_MODEL))[tid];
    ushort4 o;
    o.x = f2bf(xv.x); o.y = f2bf(xv.y); o.z = f2bf(xv.z); o.w = f2bf(xv.w);
    ((ushort4*)(xb + (size_t)bid * D_MODEL))[tid] = o;
    return;
  }
  __shared__ float red[4];
  if (bid < 10240) {  // W rows -> bf16 + bias dot -> Wsp
    const bool isq = bid < 9216;
    const int row = bid - (isq ? 8192 : 9216);
    const float* W = isq ? Wq : Wk;
    const float* bias = isq ? bk : bq;
    const float4 wv = ((const float4*)(W + (size_t)row * D_MODEL))[tid];
    const float4 bv = ((const float4*)bias)[tid];
    ushort4 o;
    o.x = f2bf(wv.x); o.y = f2bf(wv.y); o.z = f2bf(wv.z); o.w = f2bf(wv.w);
    ((ushort4*)((isq ? Wqb : Wkb) + (size_t)row * D_MODEL))[tid] = o;
    float p = wv.x * bv.x + wv.y * bv.y + wv.z * bv.z + wv.w * bv.w;
    #pragma unroll
    for (int off = 32; off > 0; off >>= 1) p += __shfl_down(p, off, 64);
    if ((tid & 63) == 0) red[tid >> 6] = p;
    __syncthreads();
    if (tid == 0)
      Wsp[(isq ? 0 : D_MODEL) + row] = f2bf(red[0] + red[1] + red[2] + red[3]);
    return;
  }
  // bid == 10240: sc and Wo row of Wsp
  const float4 a = ((const float4*)bq)[tid];
  const float4 b = ((const float4*)bk)[tid];
  float p = a.x * b.x + a.y * b.y + a.z * b.z + a.w * b.w;
  #pragma unroll
  for (int off = 32; off > 0; off >>= 1) p += __shfl_down(p, off, 64);
  if ((tid & 63) == 0) red[tid >> 6] = p;
  __syncthreads();
  if (tid == 0) sc[0] = SCALE * (red[0] + red[1] + red[2] + red[3]);
  const float4 wo = ((const float4*)Wo)[tid];
  ushort4 o;
  o.x = f2bf(wo.x); o.y = f2bf(wo.y); o.z = f2bf(wo.z); o.w = f2bf(wo.w);
  ((ushort4*)(Wsp + 2 * D_MODEL))[tid] = o;
}

// ---- wmm: Mt[d2,d1] = sum_e Wk[d2,e]*Wq[d1,e] ----
__global__ __launch_bounds__(256, 4) void wmm_kernel(
    const unsigned short* __restrict__ Wkb,
    const unsigned short* __restrict__ Wqb, unsigned short* __restrict__ Mt) {
  const int m0 = blockIdx.x * 128, n0 = blockIdx.y * 128;
  __shared__ unsigned short As[2 * 4096], Bs[2 * 4096];
  const int tid = threadIdx.x;
  f32x4 acc[4][4];
  #pragma unroll
  for (int i = 0; i < 4; i++)
    #pragma unroll
    for (int j = 0; j < 4; j++) acc[i][j] = f32x4{0.f, 0.f, 0.f, 0.f};
  gemm_core(stage_ptr(Wkb, m0, D_MODEL, tid), stage_ptr(Wqb, n0, D_MODEL, tid),
            D_MODEL, D_MODEL, As, Bs, tid, acc);
  store_c_bf16(acc, Mt, D_MODEL, m0, n0, tid);
}

// ---- zgen: y<8: Zb = xb @ Mt^T rows; y==8: aa/bb/tb from Wsp ----
__global__ __launch_bounds__(256, 4) void zgen_kernel(
    const unsigned short* __restrict__ xb,
    const unsigned short* __restrict__ Mt,
    const unsigned short* __restrict__ Wsp, const float* __restrict__ scp,
    const float* __restrict__ bo, unsigned short* __restrict__ Zb,
    float* __restrict__ aa, float* __restrict__ bb, float* __restrict__ tb) {
  const int m0 = blockIdx.x * 128;
  const bool special = (blockIdx.y == 8);
  const unsigned short* Bbase = special ? Wsp : Mt;
  const int n0 = special ? 0 : blockIdx.y * 128;
  __shared__ unsigned short As[2 * 4096], Bs[2 * 4096];
  const int tid = threadIdx.x;
  f32x4 acc[4][4];
  #pragma unroll
  for (int i = 0; i < 4; i++)
    #pragma unroll
    for (int j = 0; j < 4; j++) acc[i][j] = f32x4{0.f, 0.f, 0.f, 0.f};
  gemm_core(stage_ptr(xb, m0, D_MODEL, tid), stage_ptr(Bbase, n0, D_MODEL, tid),
            D_MODEL, D_MODEL, As, Bs, tid, acc);
  if (!special) {
    store_c_bf16(acc, Zb, D_MODEL, m0, n0, tid);
    return;
  }
  // special column: col0 = x.u, col1 = x.v, col2 = x.Wo
  const int lane = tid & 63, w = tid >> 6;
  const int wm = w >> 1, wn = w & 1;
  const int l16 = lane & 15, quad = lane >> 4;
  if (wn) return;
  const float scv = scp[0], bov = bo[0];
  #pragma unroll
  for (int mt = 0; mt < 4; mt++) {
    #pragma unroll
    for (int r = 0; r < 4; r++) {
      const int row = m0 + wm * 64 + mt * 16 + quad * 4 + r;
      const float val = acc[mt][0][r];
      if (l16 == 0)      aa[row] = SCALE * val + scv;
      else if (l16 == 1) bb[row] = SCALE * val;
      else if (l16 == 2) tb[row] = tanhf(val + bov);
    }
  }
}

// ---- zxt: out[b,i,j] = scale*(Z_i . x_j) + aa_i + bb_j + 5*tanh(s_j-s_i) ----
// zbase splits the batch dim across two dispatches (profiler visibility).
__global__ __launch_bounds__(256, 4) void zxt_kernel(
    const unsigned short* __restrict__ Zb, const unsigned short* __restrict__ xb,
    const float* __restrict__ tb, const float* __restrict__ aa,
    const float* __restrict__ bb, float* __restrict__ out, int zbase) {
  const int b = zbase + blockIdx.z;
  const int i0 = blockIdx.x * 128, j0 = blockIdx.y * 128;
  __shared__ unsigned short As[2 * 4096], Bs[2 * 4096];
  __shared__ float tsi[128], tsj[128], tsa[128], tsb[128];
  const int tid = threadIdx.x;
  if (tid < 128) {
    tsi[tid] = tb[b * SEQ + i0 + tid];
    tsa[tid] = aa[b * SEQ + i0 + tid];
  } else {
    tsj[tid - 128] = tb[b * SEQ + j0 + tid - 128];
    tsb[tid - 128] = bb[b * SEQ + j0 + tid - 128];
  }
  f32x4 acc[4][4];
  #pragma unroll
  for (int i = 0; i < 4; i++)
    #pragma unroll
    for (int j = 0; j < 4; j++) acc[i][j] = f32x4{0.f, 0.f, 0.f, 0.f};
  const unsigned short* A = Zb + (size_t)b * SEQ * D_MODEL;
  const unsigned short* Bt = xb + (size_t)b * SEQ * D_MODEL;
  gemm_core(stage_ptr(A, i0, D_MODEL, tid), stage_ptr(Bt, j0, D_MODEL, tid),
            D_MODEL, D_MODEL, As, Bs, tid, acc);

  const int lane = tid & 63, w = tid >> 6;
  const int wm = w >> 1, wn = w & 1;
  const int l16 = lane & 15, quad = lane >> 4;
  float tj[4], bj[4];
  #pragma unroll
  for (int nt = 0; nt < 4; nt++) {
    tj[nt] = tsj[wn * 64 + nt * 16 + l16];
    bj[nt] = tsb[wn * 64 + nt * 16 + l16];
  }
  #pragma unroll
  for (int mt = 0; mt < 4; mt++) {
    #pragma unroll
    for (int r = 0; r < 4; r++) {
      const int il = wm * 64 + mt * 16 + quad * 4 + r;
      const float ti = tsi[il];
      const float ai = tsa[il];
      float* cp = out + ((size_t)(b * SEQ + i0 + il)) * SEQ + j0 + wn * 64 + l16;
      #pragma unroll
      for (int nt = 0; nt < 4; nt++) {
        const float num = tj[nt] - ti;
        const float den = fmaf(-tj[nt], ti, 1.0f);
        const float obias = 5.0f * num * __builtin_amdgcn_rcpf(den);
        cp[nt * 16] = SCALE * acc[mt][nt][r] + ai + bj[nt] + obias;
      }
    }
  }
}

extern "C" void kernel_launch(void* const* d_in, const int* in_sizes, int n_in,
                              void* d_out, int out_size, void* d_ws, size_t ws_size,
                              hipStream_t stream) {
  const float* x  = (const float*)d_in[0];
  const float* Wq = (const float*)d_in[1];
  const float* bq = (const float*)d_in[2];
  const float* Wk = (const float*)d_in[3];
  const float* bk = (const float*)d_in[4];
  const float* Wo = (const float*)d_in[5];
  const float* bo = (const float*)d_in[6];
  float* out = (float*)d_out;

  char* ws = (char*)d_ws;
  unsigned short* xb  = (unsigned short*)(ws);                      // 16 MiB
  unsigned short* Zb  = (unsigned short*)(ws + (16ull << 20));      // 16 MiB
  unsigned short* Wqb = (unsigned short*)(ws + (32ull << 20));      // 2 MiB
  unsigned short* Wkb = (unsigned short*)(ws + (34ull << 20));      // 2 MiB
  unsigned short* Mt  = (unsigned short*)(ws + (36ull << 20));      // 2 MiB
  unsigned short* Wsp = (unsigned short*)(ws + (38ull << 20));      // 256 KiB
  float* tb = (float*)(ws + (38ull << 20) + (256ull << 10));        // 32 KiB
  float* aa = (float*)(ws + (38ull << 20) + (288ull << 10));        // 32 KiB
  float* bb = (float*)(ws + (38ull << 20) + (320ull << 10));        // 32 KiB
  float* sc = (float*)(ws + (38ull << 20) + (352ull << 10));        // 4 B

  prep_kernel<<<10241, 256, 0, stream>>>(x, Wq, Wk, bq, bk, Wo,
                                         xb, Wqb, Wkb, Wsp, sc);
  wmm_kernel<<<dim3(8, 8), 256, 0, stream>>>(Wkb, Wqb, Mt);
  zgen_kernel<<<dim3(64, 9), 256, 0, stream>>>(xb, Mt, Wsp, sc, bo,
                                               Zb, aa, bb, tb);
  zxt_kernel<<<dim3(16, 16, 2), 256, 0, stream>>>(Zb, xb, tb, aa, bb, out, 0);
  zxt_kernel<<<dim3(16, 16, 2), 256, 0, stream>>>(Zb, xb, tb, aa, bb, out, 2);
}

// Round 6
// 195.839 us; speedup vs baseline: 1.0935x; 1.0935x over previous
//
#include <hip/hip_runtime.h>
#include <math.h>

#define D_MODEL 1024
#define SEQ 2048
#define SCALE 0.03125f

using bf16x8 = __attribute__((ext_vector_type(8))) short;
using f32x4  = __attribute__((ext_vector_type(4))) float;

__device__ __forceinline__ unsigned short f2bf(float f) {
  union { float f; unsigned int u; } v; v.f = f;
  return (unsigned short)((v.u + 0x7fffu + ((v.u >> 16) & 1u)) >> 16);
}

__device__ __forceinline__ void async_cp16(const void* g, void* l) {
  __builtin_amdgcn_global_load_lds(
      (const __attribute__((address_space(1))) void*)g,
      (__attribute__((address_space(3))) void*)l, 16, 0, 0);
}

// Swizzled 128x32 bf16 tile staging (R3-verified, conflict-free + coalesced):
// thread tid stages row r0=tid>>2, seg s0=(tid&3)^((r0>>1)&3) -> LDS chunk tid
// (and row r0+64 -> chunk 256+tid). Fragment b128 reads are 2-way aliased.
__device__ __forceinline__ const unsigned short* stage_ptr(
    const unsigned short* base, int row0, int ld, int tid) {
  const int r0 = tid >> 2;
  const int s0 = ((tid & 3) ^ ((r0 >> 1) & 3)) * 8;
  return base + (size_t)(row0 + r0) * ld + s0;
}

// C[128x128] = A(rows m0..) x B^T(rows n0..), K=1024, BK=32, double-buffered
// swizzled LDS, issue-ahead staging, one barrier per iter.
__device__ __forceinline__ void gemm_core(
    const unsigned short* __restrict__ gA, const unsigned short* __restrict__ gB,
    int lda, int ldb, unsigned short* As, unsigned short* Bs, int tid,
    f32x4 acc[4][4]) {
  const int lane = tid & 63, w = tid >> 6;
  const int wm = w >> 1, wn = w & 1;
  const int l16 = lane & 15, quad = lane >> 4;

  async_cp16(gA,            As + tid * 8);
  async_cp16(gA + 64 * lda, As + 2048 + tid * 8);
  async_cp16(gB,            Bs + tid * 8);
  async_cp16(gB + 64 * ldb, Bs + 2048 + tid * 8);
  __syncthreads();

  #pragma unroll 2
  for (int kk = 0; kk < 32; ++kk) {
    const int cur = (kk & 1) * 4096;
    const int nxt = 4096 - cur;
    if (kk < 31) {
      const unsigned short* a = gA + (kk + 1) * 32;
      const unsigned short* b = gB + (kk + 1) * 32;
      async_cp16(a,            As + nxt + tid * 8);
      async_cp16(a + 64 * lda, As + nxt + 2048 + tid * 8);
      async_cp16(b,            Bs + nxt + tid * 8);
      async_cp16(b + 64 * ldb, Bs + nxt + 2048 + tid * 8);
    }
    bf16x8 afr[4], bfr[4];
    #pragma unroll
    for (int mt = 0; mt < 4; mt++) {
      const int R = wm * 64 + mt * 16 + l16;
      afr[mt] = *(const bf16x8*)(As + cur + (R * 4 + (quad ^ ((R >> 1) & 3))) * 8);
    }
    #pragma unroll
    for (int nt = 0; nt < 4; nt++) {
      const int R = wn * 64 + nt * 16 + l16;
      bfr[nt] = *(const bf16x8*)(Bs + cur + (R * 4 + (quad ^ ((R >> 1) & 3))) * 8);
    }
    #pragma unroll
    for (int mt = 0; mt < 4; mt++)
      #pragma unroll
      for (int nt = 0; nt < 4; nt++)
        acc[mt][nt] = __builtin_amdgcn_mfma_f32_16x16x32_bf16(
            afr[mt], bfr[nt], acc[mt][nt], 0, 0, 0);
    __syncthreads();
  }
}

__device__ __forceinline__ void store_c_bf16(f32x4 acc[4][4],
                                             unsigned short* C, int ldc,
                                             int m0, int n0, int tid) {
  const int lane = tid & 63, w = tid >> 6;
  const int wm = w >> 1, wn = w & 1;
  const int l16 = lane & 15, quad = lane >> 4;
  #pragma unroll
  for (int mt = 0; mt < 4; mt++) {
    #pragma unroll
    for (int r = 0; r < 4; r++) {
      const int row = m0 + wm * 64 + mt * 16 + quad * 4 + r;
      unsigned short* cp = C + (size_t)row * ldc + n0 + wn * 64 + l16;
      #pragma unroll
      for (int nt = 0; nt < 4; nt++) cp[nt * 16] = f2bf(acc[mt][nt][r]);
    }
  }
}

// ---- prep: xb=bf16(x); Wqb/Wkb=bf16(W); Wsp rows {u=Wq.bk, v=Wk.bq, Wo};
//      sc = scale*(bq.bk). Pure streaming, no cross-kernel deps upstream. ----
__global__ __launch_bounds__(256) void prep_kernel(
    const float* __restrict__ x, const float* __restrict__ Wq,
    const float* __restrict__ Wk, const float* __restrict__ bq,
    const float* __restrict__ bk, const float* __restrict__ Wo,
    unsigned short* __restrict__ xb, unsigned short* __restrict__ Wqb,
    unsigned short* __restrict__ Wkb, unsigned short* __restrict__ Wsp,
    float* __restrict__ sc) {
  const int bid = blockIdx.x, tid = threadIdx.x;
  if (bid < 8192) {  // x rows -> bf16
    const float4 xv = ((const float4*)(x + (size_t)bid * D_MODEL))[tid];
    ushort4 o;
    o.x = f2bf(xv.x); o.y = f2bf(xv.y); o.z = f2bf(xv.z); o.w = f2bf(xv.w);
    ((ushort4*)(xb + (size_t)bid * D_MODEL))[tid] = o;
    return;
  }
  __shared__ float red[4];
  if (bid < 10240) {  // W rows -> bf16 + bias dot -> Wsp
    const bool isq = bid < 9216;
    const int row = bid - (isq ? 8192 : 9216);
    const float* W = isq ? Wq : Wk;
    const float* bias = isq ? bk : bq;
    const float4 wv = ((const float4*)(W + (size_t)row * D_MODEL))[tid];
    const float4 bv = ((const float4*)bias)[tid];
    ushort4 o;
    o.x = f2bf(wv.x); o.y = f2bf(wv.y); o.z = f2bf(wv.z); o.w = f2bf(wv.w);
    ((ushort4*)((isq ? Wqb : Wkb) + (size_t)row * D_MODEL))[tid] = o;
    float p = wv.x * bv.x + wv.y * bv.y + wv.z * bv.z + wv.w * bv.w;
    #pragma unroll
    for (int off = 32; off > 0; off >>= 1) p += __shfl_down(p, off, 64);
    if ((tid & 63) == 0) red[tid >> 6] = p;
    __syncthreads();
    if (tid == 0)
      Wsp[(isq ? 0 : D_MODEL) + row] = f2bf(red[0] + red[1] + red[2] + red[3]);
    return;
  }
  // bid == 10240: sc and Wo row of Wsp
  const float4 a = ((const float4*)bq)[tid];
  const float4 b = ((const float4*)bk)[tid];
  float p = a.x * b.x + a.y * b.y + a.z * b.z + a.w * b.w;
  #pragma unroll
  for (int off = 32; off > 0; off >>= 1) p += __shfl_down(p, off, 64);
  if ((tid & 63) == 0) red[tid >> 6] = p;
  __syncthreads();
  if (tid == 0) sc[0] = SCALE * (red[0] + red[1] + red[2] + red[3]);
  const float4 wo = ((const float4*)Wo)[tid];
  ushort4 o;
  o.x = f2bf(wo.x); o.y = f2bf(wo.y); o.z = f2bf(wo.z); o.w = f2bf(wo.w);
  ((ushort4*)(Wsp + 2 * D_MODEL))[tid] = o;
}

// ---- wmm: Mt[d2,d1] = sum_e Wk[d2,e]*Wq[d1,e] ----
__global__ __launch_bounds__(256, 4) void wmm_kernel(
    const unsigned short* __restrict__ Wkb,
    const unsigned short* __restrict__ Wqb, unsigned short* __restrict__ Mt) {
  const int m0 = blockIdx.x * 128, n0 = blockIdx.y * 128;
  __shared__ unsigned short As[2 * 4096], Bs[2 * 4096];
  const int tid = threadIdx.x;
  f32x4 acc[4][4];
  #pragma unroll
  for (int i = 0; i < 4; i++)
    #pragma unroll
    for (int j = 0; j < 4; j++) acc[i][j] = f32x4{0.f, 0.f, 0.f, 0.f};
  gemm_core(stage_ptr(Wkb, m0, D_MODEL, tid), stage_ptr(Wqb, n0, D_MODEL, tid),
            D_MODEL, D_MODEL, As, Bs, tid, acc);
  store_c_bf16(acc, Mt, D_MODEL, m0, n0, tid);
}

// ---- zgen: y<8: Zb = xb @ Mt^T rows; y==8: aa/bb/tb from Wsp ----
__global__ __launch_bounds__(256, 4) void zgen_kernel(
    const unsigned short* __restrict__ xb,
    const unsigned short* __restrict__ Mt,
    const unsigned short* __restrict__ Wsp, const float* __restrict__ scp,
    const float* __restrict__ bo, unsigned short* __restrict__ Zb,
    float* __restrict__ aa, float* __restrict__ bb, float* __restrict__ tb) {
  const int m0 = blockIdx.x * 128;
  const bool special = (blockIdx.y == 8);
  const unsigned short* Bbase = special ? Wsp : Mt;
  const int n0 = special ? 0 : blockIdx.y * 128;
  __shared__ unsigned short As[2 * 4096], Bs[2 * 4096];
  const int tid = threadIdx.x;
  f32x4 acc[4][4];
  #pragma unroll
  for (int i = 0; i < 4; i++)
    #pragma unroll
    for (int j = 0; j < 4; j++) acc[i][j] = f32x4{0.f, 0.f, 0.f, 0.f};
  gemm_core(stage_ptr(xb, m0, D_MODEL, tid), stage_ptr(Bbase, n0, D_MODEL, tid),
            D_MODEL, D_MODEL, As, Bs, tid, acc);
  if (!special) {
    store_c_bf16(acc, Zb, D_MODEL, m0, n0, tid);
    return;
  }
  // special column: col0 = x.u, col1 = x.v, col2 = x.Wo
  const int lane = tid & 63, w = tid >> 6;
  const int wm = w >> 1, wn = w & 1;
  const int l16 = lane & 15, quad = lane >> 4;
  if (wn) return;
  const float scv = scp[0], bov = bo[0];
  #pragma unroll
  for (int mt = 0; mt < 4; mt++) {
    #pragma unroll
    for (int r = 0; r < 4; r++) {
      const int row = m0 + wm * 64 + mt * 16 + quad * 4 + r;
      const float val = acc[mt][0][r];
      if (l16 == 0)      aa[row] = SCALE * val + scv;
      else if (l16 == 1) bb[row] = SCALE * val;
      else if (l16 == 2) tb[row] = tanhf(val + bov);
    }
  }
}

// ---- zxt: out[b,i,j] = scale*(Z_i . x_j) + aa_i + bb_j + 5*tanh(s_j-s_i) ----
__global__ __launch_bounds__(256, 4) void zxt_kernel(
    const unsigned short* __restrict__ Zb, const unsigned short* __restrict__ xb,
    const float* __restrict__ tb, const float* __restrict__ aa,
    const float* __restrict__ bb, float* __restrict__ out) {
  const int b = blockIdx.z;
  const int i0 = blockIdx.x * 128, j0 = blockIdx.y * 128;
  __shared__ unsigned short As[2 * 4096], Bs[2 * 4096];
  __shared__ float tsi[128], tsj[128], tsa[128], tsb[128];
  const int tid = threadIdx.x;
  if (tid < 128) {
    tsi[tid] = tb[b * SEQ + i0 + tid];
    tsa[tid] = aa[b * SEQ + i0 + tid];
  } else {
    tsj[tid - 128] = tb[b * SEQ + j0 + tid - 128];
    tsb[tid - 128] = bb[b * SEQ + j0 + tid - 128];
  }
  f32x4 acc[4][4];
  #pragma unroll
  for (int i = 0; i < 4; i++)
    #pragma unroll
    for (int j = 0; j < 4; j++) acc[i][j] = f32x4{0.f, 0.f, 0.f, 0.f};
  const unsigned short* A = Zb + (size_t)b * SEQ * D_MODEL;
  const unsigned short* Bt = xb + (size_t)b * SEQ * D_MODEL;
  gemm_core(stage_ptr(A, i0, D_MODEL, tid), stage_ptr(Bt, j0, D_MODEL, tid),
            D_MODEL, D_MODEL, As, Bs, tid, acc);

  const int lane = tid & 63, w = tid >> 6;
  const int wm = w >> 1, wn = w & 1;
  const int l16 = lane & 15, quad = lane >> 4;
  float tj[4], bj[4];
  #pragma unroll
  for (int nt = 0; nt < 4; nt++) {
    tj[nt] = tsj[wn * 64 + nt * 16 + l16];
    bj[nt] = tsb[wn * 64 + nt * 16 + l16];
  }
  #pragma unroll
  for (int mt = 0; mt < 4; mt++) {
    #pragma unroll
    for (int r = 0; r < 4; r++) {
      const int il = wm * 64 + mt * 16 + quad * 4 + r;
      const float ti = tsi[il];
      const float ai = tsa[il];
      float* cp = out + ((size_t)(b * SEQ + i0 + il)) * SEQ + j0 + wn * 64 + l16;
      #pragma unroll
      for (int nt = 0; nt < 4; nt++) {
        const float num = tj[nt] - ti;
        const float den = fmaf(-tj[nt], ti, 1.0f);
        const float obias = 5.0f * num * __builtin_amdgcn_rcpf(den);
        cp[nt * 16] = SCALE * acc[mt][nt][r] + ai + bj[nt] + obias;
      }
    }
  }
}

extern "C" void kernel_launch(void* const* d_in, const int* in_sizes, int n_in,
                              void* d_out, int out_size, void* d_ws, size_t ws_size,
                              hipStream_t stream) {
  const float* x  = (const float*)d_in[0];
  const float* Wq = (const float*)d_in[1];
  const float* bq = (const float*)d_in[2];
  const float* Wk = (const float*)d_in[3];
  const float* bk = (const float*)d_in[4];
  const float* Wo = (const float*)d_in[5];
  const float* bo = (const float*)d_in[6];
  float* out = (float*)d_out;

  char* ws = (char*)d_ws;
  unsigned short* xb  = (unsigned short*)(ws);                      // 16 MiB
  unsigned short* Zb  = (unsigned short*)(ws + (16ull << 20));      // 16 MiB
  unsigned short* Wqb = (unsigned short*)(ws + (32ull << 20));      // 2 MiB
  unsigned short* Wkb = (unsigned short*)(ws + (34ull << 20));      // 2 MiB
  unsigned short* Mt  = (unsigned short*)(ws + (36ull << 20));      // 2 MiB
  unsigned short* Wsp = (unsigned short*)(ws + (38ull << 20));      // 256 KiB
  float* tb = (float*)(ws + (38ull << 20) + (256ull << 10));        // 32 KiB
  float* aa = (float*)(ws + (38ull << 20) + (288ull << 10));        // 32 KiB
  float* bb = (float*)(ws + (38ull << 20) + (320ull << 10));        // 32 KiB
  float* sc = (float*)(ws + (38ull << 20) + (352ull << 10));        // 4 B

  prep_kernel<<<10241, 256, 0, stream>>>(x, Wq, Wk, bq, bk, Wo,
                                         xb, Wqb, Wkb, Wsp, sc);
  wmm_kernel<<<dim3(8, 8), 256, 0, stream>>>(Wkb, Wqb, Mt);
  zgen_kernel<<<dim3(64, 9), 256, 0, stream>>>(xb, Mt, Wsp, sc, bo,
                                               Zb, aa, bb, tb);
  zxt_kernel<<<dim3(16, 16, 4), 256, 0, stream>>>(Zb, xb, tb, aa, bb, out);
}